// Round 12
// baseline (29.192 us; speedup 1.0000x reference)
//
#include <hip/hip_runtime.h>
#include <hip/hip_bf16.h>
#include <math.h>

#define D_IN  128
#define NH    8
#define F_OUT 32
#define HID   256
#define D_EMB 64
#define BINS  200
#define FDIM  384
#define CAP   128
#define SNF   48      // matched nf rows staged in LDS (E[cnt]=32; e>=SNF falls back to global)

#define NSTAGE 8      // blocks 0..7: one per head, never scan
#define NSCANB 248    // blocks 8..255: scan
#define GRID   256    // 1 block/CU -> all co-resident, poll-wait is deadlock-safe

#define AR __ATOMIC_RELAXED
#define SA __HIP_MEMORY_SCOPE_AGENT
#define STF(p, v) __hip_atomic_store((p), (v), AR, SA)   // write-through at IC
#define LDF(p)    __hip_atomic_load((p), AR, SA)         // read-through at IC

// ws ints: [0]=count [1]=done [2]=flag_mlp ; done_proj[8] @+8 ;
//          m_src @+64 (CAP) ; m_trg @+192 ; m_bin @+320
// ws floats (fb = (float*)d_ws + 1024): out_ws[512] ; partial[8] @+512

__device__ __forceinline__ float redw(float v) {
#pragma unroll
  for (int o = 32; o > 0; o >>= 1) v += __shfl_down(v, o, 64);
  return v;
}
__device__ __forceinline__ float red16(float v) {
#pragma unroll
  for (int o = 8; o > 0; o >>= 1) v += __shfl_down(v, o, 16);
  return v;
}
__device__ __forceinline__ void vm0() {
  asm volatile("s_waitcnt vmcnt(0)" ::: "memory");
}

__global__ void zero_k(int* w) { if (threadIdx.x < 16) w[threadIdx.x] = 0; }

__global__ __launch_bounds__(512, 1) void fused_k(
    const float* __restrict__ nf, const int* __restrict__ esrc,
    const int* __restrict__ etrg, const int* __restrict__ ebin,
    const float* __restrict__ ms, const int* __restrict__ li_p,
    const int* __restrict__ ld_p, const int* __restrict__ dist_p,
    const float* __restrict__ Wproj, const float* __restrict__ a_src,
    const float* __restrict__ a_trg, const float* __restrict__ Wms,
    const float* __restrict__ demb_g, const float* __restrict__ Wdist,
    const float* __restrict__ Wskip, const float* __restrict__ gbias,
    const float* __restrict__ demb_h, const float* __restrict__ W1,
    const float* __restrict__ b1, const float* __restrict__ W2,
    const float* __restrict__ b2, int nE,
    int* __restrict__ ws_i, float* __restrict__ fb, float* __restrict__ out) {
  int* count     = ws_i;
  int* done      = ws_i + 1;
  int* flag_mlp  = ws_i + 2;
  int* done_proj = ws_i + 8;
  int* m_src     = ws_i + 64;
  int* m_trg     = ws_i + 192;
  int* m_bin     = ws_i + 320;
  float* out_ws  = fb;
  float* partial = fb + 512;

  // stage-block LDS (~56 KB; scan blocks ignore it, 1 block/CU anyway)
  __shared__ __align__(16) float s_wp[F_OUT * D_IN];    // 16 KB Wproj rows of head h
  __shared__ __align__(16) float s_w1e[F_OUT * D_EMB];  // 8 KB  W1[:,256:320) rows
  __shared__ __align__(16) float s_nfe[SNF * D_IN];     // 24 KB matched nf rows
  __shared__ __align__(16) float s_nf2[2 * D_IN];       // nf[li], nf[ld]
  __shared__ float s_vs[D_IN], s_vt[D_IN];
  __shared__ float s_wd[D_EMB];
  __shared__ int   s_ms[CAP], s_tb[CAP], s_bn[CAP];
  __shared__ float s_p[CAP];
  __shared__ float s_den[2];
  __shared__ float s_misc[3];                           // strg0, strg1, sms_h
  __shared__ float s_p1[F_OUT], s_sk0[F_OUT], s_sk1[F_OUT];
  __shared__ __align__(16) float s_agg[2 * D_IN];
  __shared__ __align__(16) float s_out[512];
  __shared__ __align__(16) float s_emb[2 * F_OUT];
  __shared__ float s_pr[8];

  const int bid = blockIdx.x, tid = threadIdx.x;
  const int wv = tid >> 6, ln = tid & 63;
  const int li = li_p[0], ld = ld_p[0];

  if (bid >= NSTAGE) {
    // ===================== SCAN block =====================
    const int sid = bid - NSTAGE;
    const int gid = sid * 512 + tid;
    const int stride = NSCANB * 512;
    const int nE4 = nE >> 2;
    const int4* t4 = (const int4*)etrg;
    for (int e4 = gid; e4 < nE4; e4 += stride) {
      int4 t = t4[e4];
      int ev[4] = {t.x, t.y, t.z, t.w};
#pragma unroll
      for (int k = 0; k < 4; ++k) {
        if (ev[k] == li || ev[k] == ld) {
          int e = e4 * 4 + k;
          int pos = __hip_atomic_fetch_add(count, 1, AR, SA);
          if (pos < CAP) {
            STF(m_src + pos, esrc[e]);
            STF(m_trg + pos, ev[k]);
            STF(m_bin + pos, ebin[e]);
          }
        }
      }
    }
    if (sid == 0 && tid == 0) {            // tail (nE % 4)
      for (int e = nE4 * 4; e < nE; ++e) {
        int tv = etrg[e];
        if (tv == li || tv == ld) {
          int pos = __hip_atomic_fetch_add(count, 1, AR, SA);
          if (pos < CAP) { STF(m_src + pos, esrc[e]); STF(m_trg + pos, tv); STF(m_bin + pos, ebin[e]); }
        }
      }
    }
    vm0();                                  // publications acked at IC
    __syncthreads();
    if (tid == 0) __hip_atomic_fetch_add(done, 1, AR, SA);
    return;
  }

  // ===================== STAGE block (head h) =====================
  const int h = bid;
  const int dist = dist_p[0];

  // ---- phase A: prefetch read-only tiles (plain cached loads) ----
  {
    const float4* src = (const float4*)(Wproj + (size_t)h * F_OUT * D_IN);
    float4* dst = (float4*)s_wp;
    for (int i = tid; i < F_OUT * D_IN / 4; i += 512) dst[i] = src[i];
  }
  {
    const int r = tid >> 4, q = tid & 15;   // 32 rows x 16 quads
    ((float4*)s_w1e)[tid] =
        *(const float4*)(W1 + (size_t)(h * F_OUT + r) * FDIM + HID + q * 4);
  }
  if (tid < 64)
    ((float4*)s_nf2)[tid] = ((const float4*)(nf + (size_t)(tid < 32 ? li : ld) * D_IN))[tid & 31];
  if (tid >= 64 && tid < 128) s_wd[tid - 64] = Wdist[h * D_EMB + tid - 64];
  __syncthreads();

  // ---- phase B: scan-independent precompute (runs under the scan window) ----
  {  // pre1[r] = W1[r,0:256].ms + W1[r,320:384].demb_h[dist] + b1[r]
    const int rr = tid >> 4, q = tid & 15;
    const int r = h * F_OUT + rr;
    const float* w = W1 + (size_t)r * FDIM;
    float acc = 0.f;
    const float4* wm = (const float4*)(w + q * 16);
    const float4* mv = (const float4*)(ms + q * 16);
#pragma unroll
    for (int i = 0; i < 4; ++i) {
      float4 a = wm[i], x = mv[i];
      acc = fmaf(a.x, x.x, acc); acc = fmaf(a.y, x.y, acc);
      acc = fmaf(a.z, x.z, acc); acc = fmaf(a.w, x.w, acc);
    }
    const float* wd2 = w + HID + 2 * F_OUT + q * 4;
    const float* dv = demb_h + (size_t)dist * D_EMB + q * 4;
#pragma unroll
    for (int i = 0; i < 4; ++i) acc = fmaf(wd2[i], dv[i], acc);
    acc = red16(acc);
    if (q == 0) s_p1[rr] = acc + b1[r];
  }
  {  // skip: sk_t[r] = Wskip[r] . nf_t
    const int rr = tid >> 4, q = tid & 15;
    const float* wk = Wskip + (size_t)(h * F_OUT + rr) * D_IN + q * 8;
    float a0 = 0.f, a1 = 0.f;
#pragma unroll
    for (int c = 0; c < 8; ++c) {
      float w = wk[c];
      a0 = fmaf(w, s_nf2[q * 8 + c], a0);
      a1 = fmaf(w, s_nf2[128 + q * 8 + c], a1);
    }
    a0 = red16(a0); a1 = red16(a1);
    if (q == 0) { s_sk0[rr] = a0; s_sk1[rr] = a1; }
  }
  if (tid < 128) {  // vsrc/vtrg[d] = sum_f a_*[h,f] * Wp[f][d]
    float vs = 0.f, vt = 0.f;
    for (int f = 0; f < F_OUT; ++f) {
      float w = s_wp[f * D_IN + tid];
      vs = fmaf(a_src[h * F_OUT + f], w, vs);
      vt = fmaf(a_trg[h * F_OUT + f], w, vt);
    }
    s_vs[tid] = vs; s_vt[tid] = vt;
  }
  __syncthreads();
  if (wv < 2) {     // strg[t] = nf_t . vtrg
    float part = s_nf2[wv * 128 + ln * 2] * s_vt[ln * 2]
               + s_nf2[wv * 128 + ln * 2 + 1] * s_vt[ln * 2 + 1];
    part = redw(part);
    if (ln == 0) s_misc[wv] = part;
  } else if (wv == 2) {  // sms_h = Wms[h] . ms
    float a = 0.f;
#pragma unroll
    for (int m = 0; m < 4; ++m) a = fmaf(Wms[h * HID + ln + 64 * m], ms[ln + 64 * m], a);
    a = redw(a);
    if (ln == 0) s_misc[2] = a;
  }
  __syncthreads();

  // ---- wait for scan completion (single word, read-spin) ----
  if (tid == 0) {
    while (LDF(done) < NSCANB) __builtin_amdgcn_s_sleep(2);
  }
  __syncthreads();

  // ---- scan results: 1 concurrent RT ----
  int cnt = LDF(count); if (cnt > CAP) cnt = CAP;
  if (tid < cnt) {
    s_ms[tid] = LDF(m_src + tid);
    s_tb[tid] = (LDF(m_trg + tid) == li) ? 0 : 1;
    s_bn[tid] = LDF(m_bin + tid);
  }
  __syncthreads();

  // ---- gather matched nf rows (read-only input -> plain loads) ----
  {
    const int lim = (cnt < SNF ? cnt : SNF) * 32;
    float4* dst = (float4*)s_nfe;
    for (int i4 = tid; i4 < lim; i4 += 512)
      dst[i4] = ((const float4*)nf)[(size_t)s_ms[i4 >> 5] * 32 + (i4 & 31)];
  }
  __syncthreads();

  // ---- scores: exp(leaky_relu(nf.vsrc + strg + sms + demb.wd)) ----
  // (reference's global max cancels in exp_s/denom)
  const float strg0 = s_misc[0], strg1 = s_misc[1], sms_h = s_misc[2];
  for (int e = wv; e < cnt; e += 8) {
    float x0, x1;
    if (e < SNF) { x0 = s_nfe[e * D_IN + ln * 2]; x1 = s_nfe[e * D_IN + ln * 2 + 1]; }
    else {
      const float* g = nf + (size_t)s_ms[e] * D_IN + ln * 2;
      x0 = g[0]; x1 = g[1];
    }
    float part = x0 * s_vs[ln * 2] + x1 * s_vs[ln * 2 + 1]
               + demb_g[(size_t)s_bn[e] * D_EMB + ln] * s_wd[ln];
    part = redw(part);
    if (ln == 0) {
      float sc = part + (s_tb[e] ? strg1 : strg0) + sms_h;
      sc = sc > 0.f ? sc : 0.2f * sc;
      s_p[e] = expf(sc);
    }
  }
  __syncthreads();
  if (tid < 2) {
    float d = 1e-16f;
    for (int e = 0; e < cnt; ++e) if (s_tb[e] == (int)tid) d += s_p[e];
    s_den[tid] = d;
  }
  __syncthreads();
  if (tid < cnt) s_p[tid] = s_p[tid] / s_den[s_tb[tid]];
  __syncthreads();
  if (tid < 256) {   // agg[t][d] = sum_e attn * nf_row[d]
    const int t = tid >> 7, d = tid & 127;
    float a = 0.f;
    for (int e = 0; e < cnt; ++e) {
      if (s_tb[e] == t) {
        float v = (e < SNF) ? s_nfe[e * D_IN + d] : nf[(size_t)s_ms[e] * D_IN + d];
        a = fmaf(s_p[e], v, a);
      }
    }
    s_agg[t * D_IN + d] = a;
  }
  __syncthreads();

  // ---- proj: 32 rows of this head from LDS Wp tile ----
#pragma unroll
  for (int j = 0; j < 4; ++j) {
    const int f = wv * 4 + j, r = h * F_OUT + f;
    float o0 = s_wp[f * D_IN + ln * 2] * s_agg[ln * 2]
             + s_wp[f * D_IN + ln * 2 + 1] * s_agg[ln * 2 + 1];
    float o1 = s_wp[f * D_IN + ln * 2] * s_agg[128 + ln * 2]
             + s_wp[f * D_IN + ln * 2 + 1] * s_agg[128 + ln * 2 + 1];
    o0 = redw(o0); o1 = redw(o1);
    if (ln == 0) {
      STF(out_ws + r,       o0 + s_sk0[f]);
      STF(out_ws + 256 + r, o1 + s_sk1[f]);
    }
  }
  // ---- 8-way proj handoff: distinct done-words, read-spin ----
  vm0();
  __syncthreads();
  if (tid == 0) STF(done_proj + h, 1);
  if (tid < NSTAGE)
    while (LDF(done_proj + tid) == 0) __builtin_amdgcn_s_sleep(1);
  __syncthreads();

  // ---- MLP ----
  s_out[tid] = LDF(out_ws + tid);
  __syncthreads();
  if (tid < 64) {    // head-mean + bias + ELU
    const int t = tid >> 5, f = tid & 31;
    float s = 0.f;
#pragma unroll
    for (int hh = 0; hh < NH; ++hh) s += s_out[t * 256 + hh * F_OUT + f];
    s = s * 0.125f + gbias[f];
    s_emb[tid] = s > 0.f ? s : expm1f(s);
  }
  __syncthreads();
  {
    float bp = 0.f;
#pragma unroll
    for (int j = 0; j < 4; ++j) {
      const int f = wv * 4 + j;
      float acc = redw(s_w1e[f * D_EMB + ln] * s_emb[ln]);
      if (ln == 0) {
        float h1 = fmaxf(s_p1[f] + acc, 0.f);
        bp += W2[h * F_OUT + f] * h1;
      }
    }
    if (ln == 0) s_pr[wv] = bp;
  }
  __syncthreads();
  if (tid == 0) {
    float bp = 0.f;
#pragma unroll
    for (int w = 0; w < 8; ++w) bp += s_pr[w];
    STF(partial + h, bp);
    vm0();
    int ret = __hip_atomic_fetch_add(flag_mlp, 1, AR, SA);
    if (ret == NSTAGE - 1) {   // last block finalizes
      float s = b2[0];
      for (int j = 0; j < NSTAGE; ++j) s += LDF(partial + j);
      out[0] = s;
    }
  }
}

extern "C" void kernel_launch(void* const* d_in, const int* in_sizes, int n_in,
                              void* d_out, int out_size, void* d_ws, size_t ws_size,
                              hipStream_t stream) {
  const float* nf     = (const float*)d_in[0];
  const int*   esrc   = (const int*)d_in[1];
  const int*   etrg   = (const int*)d_in[2];
  const int*   ebin   = (const int*)d_in[3];
  const float* ms     = (const float*)d_in[4];
  const int*   li_p   = (const int*)d_in[5];
  const int*   ld_p   = (const int*)d_in[6];
  const int*   dist_p = (const int*)d_in[7];
  const float* Wproj  = (const float*)d_in[8];
  const float* a_src  = (const float*)d_in[9];
  const float* a_trg  = (const float*)d_in[10];
  const float* Wms    = (const float*)d_in[11];
  const float* demb_g = (const float*)d_in[12];
  const float* Wdist  = (const float*)d_in[13];
  const float* Wskip  = (const float*)d_in[14];
  const float* gbias  = (const float*)d_in[15];
  const float* demb_h = (const float*)d_in[16];
  const float* W1     = (const float*)d_in[17];
  const float* b1     = (const float*)d_in[18];
  const float* W2     = (const float*)d_in[19];
  const float* b2     = (const float*)d_in[20];
  const int nE = in_sizes[1];

  int*   ws_i = (int*)d_ws;
  float* fb   = (float*)d_ws + 1024;

  zero_k<<<1, 64, 0, stream>>>(ws_i);

  fused_k<<<GRID, 512, 0, stream>>>(
      nf, esrc, etrg, ebin, ms, li_p, ld_p, dist_p,
      Wproj, a_src, a_trg, Wms, demb_g, Wdist, Wskip, gbias, demb_h,
      W1, b1, W2, b2, nE, ws_i, fb, (float*)d_out);
}

// Round 13
// 25.939 us; speedup vs baseline: 1.1254x; 1.1254x over previous
//
#include <hip/hip_runtime.h>
#include <hip/hip_bf16.h>
#include <math.h>

#define D_IN  128
#define NH    8
#define F_OUT 32
#define HID   256
#define D_EMB 64
#define BINS  200
#define FDIM  384
#define CAP   128
#define SLOTS 6

// ---- K1 grid (256 blocks): 219 scan + 37 pre ----
#define NSCANB 219
#define VSRC_B 219   // 8 blocks : vsrc + strg   (block 219 also zeroes K2 flags)
#define SKIP_B 227   // 8 blocks : skipb
#define ESC_B  235   // 4 blocks : escall
#define SMS_B  239   // 1 block  : sms
#define PRE1_B 240   // 16 blocks: pre1 -> 256
#define K1GRID 256
#define K2GRID 32

#define AR __ATOMIC_RELAXED
#define SA __HIP_MEMORY_SCOPE_AGENT
#define STF(p, v) __hip_atomic_store((p), (v), AR, SA)
#define LDF(p)    __hip_atomic_load((p), AR, SA)

// ---- ws layout ----
// ints (ws_i): [0]=flag_proj [1]=flag_mlp
//   bcnt:  +16   (219)
//   bsrc:  +256  (219*6=1314)
//   btrg:  +1600 (1314)
//   bbin:  +2944 (1314)
// floats (fb = (float*)d_ws + 8192):
//   vsrc[1024] strg[16] sms[8] escall[1600] skipb[512] pre1[256]
//   out_ws[512] partial[32]   (ends 3960)
//   bnf: fb + 4096  (219*6*128 floats, dense nf rows of matched edges)

__device__ __forceinline__ float redw(float v) {
#pragma unroll
  for (int o = 32; o > 0; o >>= 1) v += __shfl_down(v, o, 64);
  return v;
}
__device__ __forceinline__ float red32(float v) {
#pragma unroll
  for (int o = 16; o > 0; o >>= 1) v += __shfl_down(v, o, 32);
  return v;
}

__device__ __forceinline__ void vm0() {
  asm volatile("s_waitcnt vmcnt(0)" ::: "memory");
}

// =====================================================================
// K1: edge scan (private per-block slots, no global count) + pre-tasks.
// No atomics to global, no flags; kernel boundary publishes to K2.
// =====================================================================
__global__ __launch_bounds__(512, 1) void scan_pre_k(
    const float* __restrict__ nf, const int* __restrict__ esrc,
    const int* __restrict__ etrg, const int* __restrict__ ebin,
    const float* __restrict__ ms, const int* __restrict__ li_p,
    const int* __restrict__ ld_p, const int* __restrict__ dist_p,
    const float* __restrict__ Wproj, const float* __restrict__ a_src,
    const float* __restrict__ a_trg, const float* __restrict__ Wms,
    const float* __restrict__ demb_g, const float* __restrict__ Wdist,
    const float* __restrict__ Wskip, const float* __restrict__ W1,
    const float* __restrict__ b1, const float* __restrict__ demb_h,
    int nE, int* __restrict__ ws_i, float* __restrict__ fb) {
  int* bcnt = ws_i + 16;
  int* bsrc = ws_i + 256;
  int* btrg = ws_i + 1600;
  int* bbin = ws_i + 2944;
  float* vsrc   = fb;
  float* strg   = fb + 1024;
  float* sms    = fb + 1040;
  float* escall = fb + 1048;
  float* skipb  = fb + 2648;
  float* pre1   = fb + 3160;
  float* bnf    = fb + 4096;

  __shared__ __align__(16) float s_nf2[2 * D_IN];
  __shared__ __align__(16) float s_vp[2][4][D_IN];
  __shared__ int l_cnt;
  __shared__ int l_src[SLOTS], l_trg[SLOTS], l_bin[SLOTS];

  const int bid = blockIdx.x, tid = threadIdx.x;
  const int wv = tid >> 6, ln = tid & 63;
  const int li = li_p[0], ld = ld_p[0];

  if (bid < NSCANB) {
    // ===== edge scan into private slots =====
    if (tid == 0) l_cnt = 0;
    __syncthreads();
    const int gid = bid * 512 + tid;
    const int stride = NSCANB * 512;
    const int nE4 = nE >> 2;
    const int4* t4 = (const int4*)etrg;
    for (int e4 = gid; e4 < nE4; e4 += stride) {
      int4 t = t4[e4];
      int ev[4] = {t.x, t.y, t.z, t.w};
#pragma unroll
      for (int k = 0; k < 4; ++k) {
        if (ev[k] == li || ev[k] == ld) {
          int e = e4 * 4 + k;
          int p = atomicAdd(&l_cnt, 1);
          if (p < SLOTS) { l_src[p] = esrc[e]; l_trg[p] = ev[k]; l_bin[p] = ebin[e]; }
        }
      }
    }
    if (bid == 0 && tid == 0) {          // tail (nE % 4)
      for (int e = nE4 * 4; e < nE; ++e) {
        int tv = etrg[e];
        if (tv == li || tv == ld) {
          int p = atomicAdd(&l_cnt, 1);
          if (p < SLOTS) { l_src[p] = esrc[e]; l_trg[p] = tv; l_bin[p] = ebin[e]; }
        }
      }
    }
    __syncthreads();
    int c = l_cnt; if (c > SLOTS) c = SLOTS;
    if (tid == 0) bcnt[bid] = c;         // unconditional: overwrites poison
    if (tid < c) {
      bsrc[bid * SLOTS + tid] = l_src[tid];
      btrg[bid * SLOTS + tid] = l_trg[tid];
      bbin[bid * SLOTS + tid] = l_bin[tid];
    }
    if (wv < c && ln < 32)               // dense nf-row copy (wave per match)
      ((float4*)(bnf + (size_t)(bid * SLOTS + wv) * D_IN))[ln] =
          ((const float4*)(nf + (size_t)l_src[wv] * D_IN))[ln];
    return;
  }

  if (bid < SKIP_B) {
    // ===== vsrc + strg for head h (block 219 also zeroes K2 flags) =====
    const int h = bid - VSRC_B;
    if (h == 0 && tid == 0) { ws_i[0] = 0; ws_i[1] = 0; }
    const int d = tid & 127, fg = tid >> 7;
    float as = 0.f, at = 0.f;
    for (int f = fg * 8; f < fg * 8 + 8; ++f) {
      float w = Wproj[(h * F_OUT + f) * D_IN + d];
      as = fmaf(a_src[h * F_OUT + f], w, as);
      at = fmaf(a_trg[h * F_OUT + f], w, at);
    }
    s_vp[0][fg][d] = as; s_vp[1][fg][d] = at;
    __syncthreads();
    if (tid < 128)
      vsrc[h * D_IN + tid] =
          s_vp[0][0][tid] + s_vp[0][1][tid] + s_vp[0][2][tid] + s_vp[0][3][tid];
    if (tid >= 128 && tid < 256) {
      int dd = tid - 128;
      s_vp[1][0][dd] = s_vp[1][0][dd] + s_vp[1][1][dd] + s_vp[1][2][dd] + s_vp[1][3][dd];
    }
    if (tid >= 256 && tid < 320) {
      int j = tid - 256;
      ((float4*)s_nf2)[j] = ((const float4*)(nf + (size_t)(j < 32 ? li : ld) * D_IN))[j & 31];
    }
    __syncthreads();
    if (wv < 2) {   // strg[t,h] = nf2[t] . vtrg[h]
      float part = s_nf2[wv * D_IN + ln * 2] * s_vp[1][0][ln * 2]
                 + s_nf2[wv * D_IN + ln * 2 + 1] * s_vp[1][0][ln * 2 + 1];
      part = redw(part);
      if (ln == 0) strg[wv * NH + h] = part;
    }
  } else if (bid < ESC_B) {
    // ===== skipb rows [32p, 32p+32) =====
    const int base = (bid - SKIP_B) * 32;
    if (tid < 64)
      ((float4*)s_nf2)[tid] = ((const float4*)(nf + (size_t)(tid < 32 ? li : ld) * D_IN))[tid & 31];
    __syncthreads();
    for (int rd = 0; rd < 4; ++rd) {
      int r = base + rd * 8 + wv;
      float w0 = Wskip[r * D_IN + ln * 2], w1 = Wskip[r * D_IN + ln * 2 + 1];
      float o0 = w0 * s_nf2[ln * 2] + w1 * s_nf2[ln * 2 + 1];
      float o1 = w0 * s_nf2[D_IN + ln * 2] + w1 * s_nf2[D_IN + ln * 2 + 1];
      o0 = redw(o0); o1 = redw(o1);
      if (ln == 0) { skipb[r] = o0; skipb[256 + r] = o1; }
    }
  } else if (bid < SMS_B) {
    // ===== escall bins [50p, 50p+50) =====
    const int p = bid - ESC_B;
    const int g = tid >> 3, l8 = tid & 7;
    for (int it = g; it < 50 * NH; it += 64) {
      int bin = p * 50 + (it >> 3), hh = it & 7;
      const float* de = demb_g + bin * D_EMB + l8 * 8;
      const float* wd = Wdist + hh * D_EMB + l8 * 8;
      float a = 0.f;
#pragma unroll
      for (int j = 0; j < 8; ++j) a = fmaf(de[j], wd[j], a);
#pragma unroll
      for (int o = 4; o > 0; o >>= 1) a += __shfl_down(a, o, 8);
      if (l8 == 0) escall[bin * NH + hh] = a;
    }
  } else if (bid < PRE1_B) {
    // ===== sms[h] = Wms[h] . ms (wave per head) =====
    const float* wr = Wms + wv * HID;
    float a = 0.f;
#pragma unroll
    for (int m = 0; m < 4; ++m) a = fmaf(wr[ln + 64 * m], ms[ln + 64 * m], a);
    a = redw(a);
    if (ln == 0) sms[wv] = a;
  } else {
    // ===== pre1 rows [16q, 16q+16) =====
    const int q = bid - PRE1_B;
    const int dist = dist_p[0];
    for (int rr = 0; rr < 2; ++rr) {
      int r = q * 16 + wv * 2 + rr;
      const float* w = W1 + (size_t)r * FDIM;
      float a = 0.f;
#pragma unroll
      for (int m = 0; m < 4; ++m) a = fmaf(w[ln + 64 * m], ms[ln + 64 * m], a);
      a = fmaf(w[320 + ln], demb_h[(size_t)dist * D_EMB + ln], a);
      a = redw(a);
      if (ln == 0) pre1[r] = a + b1[r];
    }
  }
}

// =====================================================================
// K2: 32 blocks; block k owns output rows [8k,8k+8) and head k>>2.
// Compacts per-block slots redundantly in LDS; dense bnf reads.
// =====================================================================
__global__ __launch_bounds__(512, 1) void finalize_k(
    const int* __restrict__ li_p,
    const float* __restrict__ Wproj, const float* __restrict__ gbias,
    const float* __restrict__ W1, const float* __restrict__ W2,
    const float* __restrict__ b2,
    int* __restrict__ ws_i, float* __restrict__ fb, float* __restrict__ out) {
  int* flag_proj = ws_i;
  int* flag_mlp  = ws_i + 1;
  int* bcnt = ws_i + 16;
  int* btrg = ws_i + 1600;
  int* bbin = ws_i + 2944;
  float* vsrc    = fb;
  float* strg    = fb + 1024;
  float* sms     = fb + 1040;
  float* escall  = fb + 1048;
  float* skipb   = fb + 2648;
  float* pre1    = fb + 3160;
  float* out_ws  = fb + 3416;
  float* partial = fb + 3928;
  float* bnf     = fb + 4096;

  __shared__ int   s_tot;
  __shared__ int   s_sl[CAP], s_tb[CAP], s_bn[CAP];
  __shared__ float s_p[CAP];
  __shared__ float s_den[2];
  __shared__ __align__(16) float s_vs[D_IN];
  __shared__ __align__(16) float s_agg[2][D_IN];
  __shared__ __align__(16) float s_out[512];
  __shared__ __align__(16) float s_emb[64];
  __shared__ float s_pr[8];

  const int k = blockIdx.x, tid = threadIdx.x;
  const int wv = tid >> 6, ln = tid & 63;
  const int li = li_p[0];
  const int h = k >> 2;
  const int row = k * 8 + wv;

  // scan-independent register preloads
  const float wpA = Wproj[row * D_IN + ln * 2];
  const float wpB = Wproj[row * D_IN + ln * 2 + 1];
  const float w1e = W1[(size_t)row * FDIM + HID + ln];
  const float w2v = W2[row];

  if (tid == 0) s_tot = 0;
  __syncthreads();
  if (tid < NSCANB) {                      // compaction of private slots
    int c = bcnt[tid];
    if (c > 0) {
      if (c > SLOTS) c = SLOTS;
      int base = atomicAdd(&s_tot, c);
      for (int j = 0; j < c; ++j)
        if (base + j < CAP) s_sl[base + j] = tid * SLOTS + j;
    }
  }
  __syncthreads();
  int cnt = s_tot; if (cnt > CAP) cnt = CAP;
  if (tid < cnt) {
    int sl = s_sl[tid];
    s_tb[tid] = (btrg[sl] == li) ? 0 : 1;
    s_bn[tid] = bbin[sl];
  }
  if (tid < D_IN) s_vs[tid] = vsrc[h * D_IN + tid];
  __syncthreads();
  const float sms_h = sms[h], strg0 = strg[h], strg1 = strg[NH + h];

  // scores: exp(leaky_relu(.)); reference's global max cancels in exp_s/denom
  for (int e = wv; e < cnt; e += 8) {
    const float* nfr = bnf + (size_t)s_sl[e] * D_IN + ln * 2;
    float part = nfr[0] * s_vs[ln * 2] + nfr[1] * s_vs[ln * 2 + 1];
    part = redw(part);
    if (ln == 0) {
      float sc = part + (s_tb[e] ? strg1 : strg0) + sms_h + escall[s_bn[e] * NH + h];
      sc = sc > 0.f ? sc : 0.2f * sc;
      s_p[e] = expf(sc);
    }
  }
  __syncthreads();
  if (tid < 2) {
    float d = 1e-16f;
    for (int e = 0; e < cnt; ++e) if (s_tb[e] == (int)tid) d += s_p[e];
    s_den[tid] = d;
  }
  __syncthreads();
  if (tid < cnt) s_p[tid] = s_p[tid] / s_den[s_tb[tid]];
  __syncthreads();
  if (tid < 256) {                         // agg[t,d] for head h (bnf L1-warm)
    const int t = tid >> 7, d = tid & 127;
    float a = 0.f;
    for (int e = 0; e < cnt; ++e)
      if (s_tb[e] == t) a = fmaf(s_p[e], bnf[(size_t)s_sl[e] * D_IN + d], a);
    s_agg[t][d] = a;
  }
  __syncthreads();
  {
    float o0 = wpA * s_agg[0][ln * 2] + wpB * s_agg[0][ln * 2 + 1];
    float o1 = wpA * s_agg[1][ln * 2] + wpB * s_agg[1][ln * 2 + 1];
    o0 = redw(o0); o1 = redw(o1);
    if (ln == 0) {
      STF(out_ws + row,       o0 + skipb[row]);
      STF(out_ws + 256 + row, o1 + skipb[256 + row]);
    }
  }
  // ---- 32-way proj barrier (relaxed flags; no fences) ----
  vm0();
  __syncthreads();
  if (tid == 0) {
    __hip_atomic_fetch_add(flag_proj, 1, AR, SA);
    while (LDF(flag_proj) < K2GRID) __builtin_amdgcn_s_sleep(1);
  }
  __syncthreads();

  // ---- MLP phase ----
  s_out[tid] = LDF(out_ws + tid);
  __syncthreads();
  if (tid < 64) {
    const int t = tid >> 5, f = tid & 31;
    float s = 0.f;
#pragma unroll
    for (int hh = 0; hh < NH; ++hh) s += s_out[t * 256 + hh * F_OUT + f];
    s = s * 0.125f + gbias[f];
    s_emb[tid] = s > 0.f ? s : expm1f(s);  // ELU
  }
  __syncthreads();
  {
    float acc = redw(w1e * s_emb[ln]);
    if (ln == 0) {
      float h1 = fmaxf(pre1[row] + acc, 0.f);
      s_pr[wv] = w2v * h1;
    }
  }
  __syncthreads();
  if (tid == 0) {
    float bp = 0.f;
#pragma unroll
    for (int w = 0; w < 8; ++w) bp += s_pr[w];
    STF(partial + k, bp);
    vm0();
    int ret = __hip_atomic_fetch_add(flag_mlp, 1, AR, SA);
    if (ret == K2GRID - 1) {               // last block finalizes
      float s = b2[0];
      for (int j = 0; j < K2GRID; ++j) s += LDF(partial + j);
      out[0] = s;
    }
  }
}

extern "C" void kernel_launch(void* const* d_in, const int* in_sizes, int n_in,
                              void* d_out, int out_size, void* d_ws, size_t ws_size,
                              hipStream_t stream) {
  const float* nf     = (const float*)d_in[0];
  const int*   esrc   = (const int*)d_in[1];
  const int*   etrg   = (const int*)d_in[2];
  const int*   ebin   = (const int*)d_in[3];
  const float* ms     = (const float*)d_in[4];
  const int*   li_p   = (const int*)d_in[5];
  const int*   ld_p   = (const int*)d_in[6];
  const int*   dist_p = (const int*)d_in[7];
  const float* Wproj  = (const float*)d_in[8];
  const float* a_src  = (const float*)d_in[9];
  const float* a_trg  = (const float*)d_in[10];
  const float* Wms    = (const float*)d_in[11];
  const float* demb_g = (const float*)d_in[12];
  const float* Wdist  = (const float*)d_in[13];
  const float* Wskip  = (const float*)d_in[14];
  const float* gbias  = (const float*)d_in[15];
  const float* demb_h = (const float*)d_in[16];
  const float* W1     = (const float*)d_in[17];
  const float* b1     = (const float*)d_in[18];
  const float* W2     = (const float*)d_in[19];
  const float* b2     = (const float*)d_in[20];
  const int nE = in_sizes[1];

  int*   ws_i = (int*)d_ws;
  float* fb   = (float*)d_ws + 8192;

  scan_pre_k<<<K1GRID, 512, 0, stream>>>(
      nf, esrc, etrg, ebin, ms, li_p, ld_p, dist_p,
      Wproj, a_src, a_trg, Wms, demb_g, Wdist, Wskip, W1, b1, demb_h,
      nE, ws_i, fb);

  finalize_k<<<K2GRID, 512, 0, stream>>>(
      li_p, Wproj, gbias, W1, W2, b2, ws_i, fb, (float*)d_out);
}